// Round 5
// baseline (189.574 us; speedup 1.0000x reference)
//
#include <hip/hip_runtime.h>
#include <cstdint>

// Problem constants (fixed by reference)
#define NT 3200   // B*N
#define NN 100    // N
#define FD 10     // F_IN
#define DD 64     // D

// ---------------- threefry2x32 (JAX PRNG), host+device ----------------
__host__ __device__ inline void tf2x32(uint32_t ks0, uint32_t ks1, uint32_t x0,
                                       uint32_t x1, uint32_t& o0, uint32_t& o1) {
  uint32_t ks2 = ks0 ^ ks1 ^ 0x1BD11BDAu;
  x0 += ks0; x1 += ks1;
#define TF_RND(r) { x0 += x1; x1 = (x1 << (r)) | (x1 >> (32 - (r))); x1 ^= x0; }
  TF_RND(13) TF_RND(15) TF_RND(26) TF_RND(6)
  x0 += ks1; x1 += ks2 + 1u;
  TF_RND(17) TF_RND(29) TF_RND(16) TF_RND(24)
  x0 += ks2; x1 += ks0 + 2u;
  TF_RND(13) TF_RND(15) TF_RND(26) TF_RND(6)
  x0 += ks0; x1 += ks1 + 3u;
  TF_RND(17) TF_RND(29) TF_RND(16) TF_RND(24)
  x0 += ks1; x1 += ks2 + 4u;
  TF_RND(13) TF_RND(15) TF_RND(26) TF_RND(6)
  x0 += ks2; x1 += ks0 + 5u;
#undef TF_RND
  o0 = x0; o1 = x1;
}

// JAX partitionable random_bits(32) for counter (0, cnt); uniform(1e-20,1); gumbel.
__device__ inline float gumbel_noise(uint32_t ka, uint32_t kb, uint32_t cnt) {
  uint32_t o0, o1;
  tf2x32(ka, kb, 0u, cnt, o0, o1);
  uint32_t bits = o0 ^ o1;
  float u = __uint_as_float((bits >> 9) | 0x3F800000u) - 1.0f;
  u = fmaxf(u, 1e-20f);
  return -logf(-logf(u));
}

// ---------------- K1: per-row prep (blocks 0..799) + static adj (800..839) ----
__global__ __launch_bounds__(256) void k_prep_adj(
    const float* __restrict__ x, const float* __restrict__ ne,
    const float* __restrict__ lW, const float* __restrict__ lb,
    const float* __restrict__ Ws, const float* __restrict__ bs,
    const float* __restrict__ as_, const float* __restrict__ Wd,
    const float* __restrict__ bd, const float* __restrict__ ad,
    float* __restrict__ h_s, float* __restrict__ h_d, float* __restrict__ nd,
    float* __restrict__ q_s, float* __restrict__ kk_s, float* __restrict__ q_d,
    float* __restrict__ kk_d, float* __restrict__ adjS,
    float* __restrict__ gstat, uint32_t k1a, uint32_t k1b) {
  __shared__ float sne[NN * 65];
  __shared__ float dnorm[NN];
  int tid = threadIdx.x, wid = tid >> 6, lane = tid & 63;
  int blk = blockIdx.x;
  if (blk < 800) {
    // wave-per-row prep: h_s, h_d, normalized dyn-emb, attention projections
    int i = blk * 4 + wid;
    const float* xr = x + i * FD;
    float hs = bs[lane], hd = bd[lane], ed = lb[lane];
#pragma unroll
    for (int f = 0; f < FD; ++f) {
      float xv = xr[f];
      hs = fmaf(xv, Ws[f * DD + lane], hs);
      hd = fmaf(xv, Wd[f * DD + lane], hd);
      ed = fmaf(xv, lW[f * DD + lane], ed);
    }
    h_s[i * DD + lane] = hs;
    h_d[i * DD + lane] = hd;
    float ss = ed * ed;
    for (int off = 32; off > 0; off >>= 1) ss += __shfl_xor(ss, off, 64);
    nd[i * DD + lane] = ed / (sqrtf(ss) + 1e-8f);
    int r = i % NN;
    float em = ne[r * DD + lane];
    float ks = hs + em, kd = hd + em;
    float qs = ks * as_[lane], kks = ks * as_[DD + lane];
    float qd = kd * ad[lane], kkd = kd * ad[DD + lane];
    for (int off = 32; off > 0; off >>= 1) {
      qs += __shfl_xor(qs, off, 64);
      kks += __shfl_xor(kks, off, 64);
      qd += __shfl_xor(qd, off, 64);
      kkd += __shfl_xor(kkd, off, 64);
    }
    if (lane == 0) { q_s[i] = qs; kk_s[i] = kks; q_d[i] = qd; kk_d[i] = kkd; }
  } else {
    if (blk == 800 && tid < 128) gstat[tid] = 0.0f;  // zero BN accumulators
    // static adjacency: stage+normalize node_emb in LDS, 100x100 decisions
    for (int idx = tid; idx < NN * DD; idx += 256)
      sne[(idx >> 6) * 65 + (idx & 63)] = ne[idx];
    __syncthreads();
    for (int row = wid; row < NN; row += 4) {
      float v = sne[row * 65 + lane];
      float ss = v * v;
      for (int off = 32; off > 0; off >>= 1) ss += __shfl_xor(ss, off, 64);
      if (lane == 0) dnorm[row] = sqrtf(ss) + 1e-8f;
    }
    __syncthreads();
    for (int idx = tid; idx < NN * DD; idx += 256) {
      int row = idx >> 6;
      sne[row * 65 + (idx & 63)] /= dnorm[row];
    }
    __syncthreads();
    int p = (blk - 800) * 256 + tid;
    if (p < NN * NN) {
      int r = p / NN, c = p - r * NN;
      float sim = 0.0f;
#pragma unroll
      for (int k = 0; k < DD; ++k)
        sim = fmaf(sne[r * 65 + k], sne[c * 65 + k], sim);
      float g0 = gumbel_noise(k1a, k1b, (uint32_t)(2 * p));
      float g1 = gumbel_noise(k1a, k1b, (uint32_t)(2 * p + 1));
      bool edge = (sim + g0 >= 1.0f - sim + g1) || (r == c);
      adjS[p] = edge ? 1.0f : 0.0f;
    }
  }
}

// ---------------- K2: wave-per-row attention, 10 rows/block ----------------
__global__ __launch_bounds__(640, 5) void k_attn(
    const float* __restrict__ h_s, const float* __restrict__ h_d,
    const float* __restrict__ nd, const float* __restrict__ q_s,
    const float* __restrict__ kk_s, const float* __restrict__ q_d,
    const float* __restrict__ kk_d, const float* __restrict__ adjS,
    const float* __restrict__ ne, float* __restrict__ o,
    float* __restrict__ gstat, uint32_t k2a, uint32_t k2b) {
  __shared__ float lA[NN * 65];   // nd, then reused for h_s
  __shared__ float lB[NN * 65];   // h_d
  __shared__ float sums[2 * 10 * 64];
  int tid = threadIdx.x, wid = tid >> 6, lane = tid & 63;
  int blk = blockIdx.x;
  int b = blk / 10, rb = (blk % 10) * 10;
  int base = b * NN;
  // stage normalized dynamic embeddings (once per 10 rows)
  for (int idx = tid; idx < NN * DD; idx += 640)
    lA[(idx >> 6) * 65 + (idx & 63)] = nd[base * DD + idx];
  __syncthreads();

  int r = rb + wid;
  int i = base + r;
  float sqs = q_s[i], sqd = q_d[i];
  int j0 = lane, j1 = lane + 64;
  bool v1 = (j1 < NN);
  int jj1 = v1 ? j1 : 0;
  // cosine sims vs row r (LDS: broadcast + stride-65 -> free 2-way)
  float sim0 = 0.0f, sim1 = 0.0f;
  const float* ndr = &lA[r * 65];
  const float* nj0 = &lA[j0 * 65];
  const float* nj1 = &lA[jj1 * 65];
#pragma unroll
  for (int k = 0; k < DD; ++k) {
    float a = ndr[k];
    sim0 = fmaf(a, nj0[k], sim0);
    sim1 = fmaf(a, nj1[k], sim1);
  }
  // static edges (precomputed adjacency)
  float es0 = -9e15f, es1 = -9e15f, ed0 = -9e15f, ed1 = -9e15f;
  if (adjS[r * NN + j0] > 0.0f) {
    float v = sqs + kk_s[base + j0];
    es0 = (v >= 0.0f) ? v : 0.2f * v;
  }
  if (v1 && adjS[r * NN + j1] > 0.0f) {
    float v = sqs + kk_s[base + j1];
    es1 = (v >= 0.0f) ? v : 0.2f * v;
  }
  // dynamic edges (gumbel on the fly)
  {
    uint32_t c0 = ((uint32_t)i * 3200u + (uint32_t)(base + j0)) * 2u;
    float g0 = gumbel_noise(k2a, k2b, c0);
    float g1 = gumbel_noise(k2a, k2b, c0 + 1u);
    if (sim0 + g0 >= 1.0f - sim0 + g1) {
      float v = sqd + kk_d[base + j0];
      ed0 = (v >= 0.0f) ? v : 0.2f * v;
    }
  }
  if (v1) {
    uint32_t c1 = ((uint32_t)i * 3200u + (uint32_t)(base + j1)) * 2u;
    float g0 = gumbel_noise(k2a, k2b, c1);
    float g1 = gumbel_noise(k2a, k2b, c1 + 1u);
    if (sim1 + g0 >= 1.0f - sim1 + g1) {
      float v = sqd + kk_d[base + j1];
      ed1 = (v >= 0.0f) ? v : 0.2f * v;
    }
  }
  // wave softmax, static
  float ms = fmaxf(es0, es1);
  for (int off = 32; off > 0; off >>= 1) ms = fmaxf(ms, __shfl_xor(ms, off, 64));
  float ws0 = expf(es0 - ms);
  float ws1 = v1 ? expf(es1 - ms) : 0.0f;
  float Ss = ws0 + ws1;
  for (int off = 32; off > 0; off >>= 1) Ss += __shfl_xor(Ss, off, 64);
  float a0s = ws0 / Ss, a1s = ws1 / Ss;
  // wave softmax, dynamic
  float md = fmaxf(ed0, ed1);
  for (int off = 32; off > 0; off >>= 1) md = fmaxf(md, __shfl_xor(md, off, 64));
  float wd0 = expf(ed0 - md);
  float wd1 = v1 ? expf(ed1 - md) : 0.0f;
  float Sd = wd0 + wd1;
  for (int off = 32; off > 0; off >>= 1) Sd += __shfl_xor(Sd, off, 64);
  float a0d = wd0 / Sd, a1d = wd1 / Sd;

  // reuse lA for h_s, lB for h_d (sims all done)
  __syncthreads();
  for (int idx = tid; idx < NN * DD; idx += 640) {
    int row = idx >> 6, ch = idx & 63;
    lA[row * 65 + ch] = h_s[base * DD + idx];
    lB[row * 65 + ch] = h_d[base * DD + idx];
  }
  __syncthreads();
  // PV: lane = channel; attention weights broadcast via shfl (same fp values,
  // same j-ascending accumulation order as r2)
  float hs = 0.0f, hd2 = 0.0f;
#pragma unroll 4
  for (int j = 0; j < 64; ++j) {
    hs = fmaf(__shfl(a0s, j, 64), lA[j * 65 + lane], hs);
    hd2 = fmaf(__shfl(a0d, j, 64), lB[j * 65 + lane], hd2);
  }
#pragma unroll 4
  for (int j = 0; j < 36; ++j) {
    hs = fmaf(__shfl(a1s, j, 64), lA[(j + 64) * 65 + lane], hs);
    hd2 = fmaf(__shfl(a1d, j, 64), lB[(j + 64) * 65 + lane], hd2);
  }
  float eS = (hs > 0.0f) ? hs : expm1f(hs);
  float eD = (hd2 > 0.0f) ? hd2 : expm1f(hd2);
  float ov = (eS + 0.01f * eD) * ne[r * DD + lane];
  o[i * DD + lane] = ov;
  // BN partials: per-block reduce across 10 waves, 128 device-scope atomics
  sums[wid * 64 + lane] = ov;
  sums[640 + wid * 64 + lane] = ov * ov;
  __syncthreads();
  if (wid == 0) {
    float s = 0.0f;
#pragma unroll
    for (int w = 0; w < 10; ++w) s += sums[w * 64 + lane];
    unsafeAtomicAdd(&gstat[lane], s);
  } else if (wid == 1) {
    float s = 0.0f;
#pragma unroll
    for (int w = 0; w < 10; ++w) s += sums[640 + w * 64 + lane];
    unsafeAtomicAdd(&gstat[64 + lane], s);
  }
}

// ---------------- K3: BN finalize + apply + ReLU + out projection ----------------
__global__ __launch_bounds__(256) void k_final(
    const float* __restrict__ o, const float* __restrict__ gstat,
    const float* __restrict__ gamma, const float* __restrict__ beta,
    const float* __restrict__ outW, const float* __restrict__ outb,
    float* __restrict__ out) {
  int tid = threadIdx.x, wid = tid >> 6, lane = tid & 63;
  int i = blockIdx.x * 4 + wid;
  float m = gstat[lane] * (1.0f / NT);
  float ex2 = gstat[64 + lane] * (1.0f / NT);
  float var = ex2 - m * m;
  float scale = gamma[lane] / sqrtf(var + 1e-5f);
  float xv = o[i * DD + lane];
  float v = (xv - m) * scale + beta[lane];
  v = fmaxf(v, 0.0f);
  float p = v * outW[lane];
  for (int off = 32; off > 0; off >>= 1) p += __shfl_xor(p, off, 64);
  if (lane == 0) out[i] = p + outb[0];
}

extern "C" void kernel_launch(void* const* d_in, const int* in_sizes, int n_in,
                              void* d_out, int out_size, void* d_ws,
                              size_t ws_size, hipStream_t stream) {
  const float* data = (const float*)d_in[0];
  const float* node_emb = (const float*)d_in[1];
  const float* lin_W = (const float*)d_in[2];
  const float* lin_b = (const float*)d_in[3];
  const float* gat_s_W = (const float*)d_in[4];
  const float* gat_s_b = (const float*)d_in[5];
  const float* gat_s_a = (const float*)d_in[6];
  const float* gat_d_W = (const float*)d_in[7];
  const float* gat_d_b = (const float*)d_in[8];
  const float* gat_d_a = (const float*)d_in[9];
  const float* bn_gamma = (const float*)d_in[10];
  const float* bn_beta = (const float*)d_in[11];
  const float* out_W = (const float*)d_in[12];
  const float* out_b = (const float*)d_in[13];
  float* out = (float*)d_out;

  float* ws = (float*)d_ws;
  float* h_s = ws;                 // NT*DD
  float* h_d = ws + 204800;        // NT*DD
  float* nd = ws + 409600;         // NT*DD
  float* q_s = ws + 614400;        // NT
  float* kk_s = ws + 617600;       // NT
  float* q_d = ws + 620800;        // NT
  float* kk_d = ws + 624000;       // NT
  float* adjS = ws + 627200;       // NN*NN
  float* o = ws + 637200;          // NT*DD
  float* gstat = ws + 842000;      // 128 (sum[64], sumsq[64])

  // JAX key(42): partitionable split -> k1=cipher(key,(0,0)), k2=cipher(key,(0,1))
  uint32_t k1a, k1b, k2a, k2b;
  tf2x32(0u, 42u, 0u, 0u, k1a, k1b);
  tf2x32(0u, 42u, 0u, 1u, k2a, k2b);

  k_prep_adj<<<840, 256, 0, stream>>>(data, node_emb, lin_W, lin_b, gat_s_W,
                                      gat_s_b, gat_s_a, gat_d_W, gat_d_b,
                                      gat_d_a, h_s, h_d, nd, q_s, kk_s, q_d,
                                      kk_d, adjS, gstat, k1a, k1b);
  k_attn<<<320, 640, 0, stream>>>(h_s, h_d, nd, q_s, kk_s, q_d, kk_d, adjS,
                                  node_emb, o, gstat, k2a, k2b);
  k_final<<<800, 256, 0, stream>>>(o, gstat, bn_gamma, bn_beta, out_W, out_b,
                                   out);
}

// Round 6
// 146.227 us; speedup vs baseline: 1.2964x; 1.2964x over previous
//
#include <hip/hip_runtime.h>
#include <cstdint>

// Problem constants (fixed by reference)
#define NT 3200   // B*N
#define NN 100    // N
#define FD 10     // F_IN
#define DD 64     // D

// ---------------- threefry2x32 (JAX PRNG), host+device ----------------
__host__ __device__ inline void tf2x32(uint32_t ks0, uint32_t ks1, uint32_t x0,
                                       uint32_t x1, uint32_t& o0, uint32_t& o1) {
  uint32_t ks2 = ks0 ^ ks1 ^ 0x1BD11BDAu;
  x0 += ks0; x1 += ks1;
#define TF_RND(r) { x0 += x1; x1 = (x1 << (r)) | (x1 >> (32 - (r))); x1 ^= x0; }
  TF_RND(13) TF_RND(15) TF_RND(26) TF_RND(6)
  x0 += ks1; x1 += ks2 + 1u;
  TF_RND(17) TF_RND(29) TF_RND(16) TF_RND(24)
  x0 += ks2; x1 += ks0 + 2u;
  TF_RND(13) TF_RND(15) TF_RND(26) TF_RND(6)
  x0 += ks0; x1 += ks1 + 3u;
  TF_RND(17) TF_RND(29) TF_RND(16) TF_RND(24)
  x0 += ks1; x1 += ks2 + 4u;
  TF_RND(13) TF_RND(15) TF_RND(26) TF_RND(6)
  x0 += ks2; x1 += ks0 + 5u;
#undef TF_RND
  o0 = x0; o1 = x1;
}

// JAX partitionable random_bits(32) for counter (0, cnt); uniform(1e-20,1); gumbel.
__device__ inline float gumbel_noise(uint32_t ka, uint32_t kb, uint32_t cnt) {
  uint32_t o0, o1;
  tf2x32(ka, kb, 0u, cnt, o0, o1);
  uint32_t bits = o0 ^ o1;
  float u = __uint_as_float((bits >> 9) | 0x3F800000u) - 1.0f;
  u = fmaxf(u, 1e-20f);
  return -logf(-logf(u));
}

// ---------------- K1: per-sample prep + ALL edge decisions + score matrices ----
// 4 blocks per sample (quarter q owns 25 rows of the score matrices).
// Each block redundantly computes the sample's prep in LDS (cheap), then
// materializes es/ed = masked leaky-relu attention logits for its rows.
__global__ __launch_bounds__(512) void k_prep(
    const float* __restrict__ x, const float* __restrict__ ne,
    const float* __restrict__ lW, const float* __restrict__ lb,
    const float* __restrict__ Ws, const float* __restrict__ bs,
    const float* __restrict__ as_, const float* __restrict__ Wd,
    const float* __restrict__ bd, const float* __restrict__ ad,
    float* __restrict__ h_s, float* __restrict__ h_d, float* __restrict__ esM,
    float* __restrict__ edM, float* __restrict__ gstat, uint32_t k1a,
    uint32_t k1b, uint32_t k2a, uint32_t k2b) {
  __shared__ float sx[NN][FD];     // sample features
  __shared__ float nen[NN * 65];   // normalized node_emb
  __shared__ float snd[NN * 65];   // normalized dynamic emb
  __shared__ float skk_s[NN], skk_d[NN], sq_s[NN], sq_d[NN], dnorm[NN];
  int tid = threadIdx.x, wid = tid >> 6, lane = tid & 63;
  int blk = blockIdx.x;
  int b = blk >> 2, q = blk & 3;
  int base = b * NN;
  if (blk == 0 && tid < 128) gstat[tid] = 0.0f;  // zero BN accumulators

  // ---- stage x and raw node_emb
  for (int idx = tid; idx < NN * FD; idx += 512)
    ((float*)sx)[idx] = x[base * FD + idx];
  for (int idx = tid; idx < NN * DD; idx += 512)
    nen[(idx >> 6) * 65 + (idx & 63)] = ne[idx];
  __syncthreads();
  // ---- normalize node_emb (identical chains to r2)
  for (int row = wid; row < NN; row += 8) {
    float v = nen[row * 65 + lane];
    float ss = v * v;
    for (int off = 32; off > 0; off >>= 1) ss += __shfl_xor(ss, off, 64);
    if (lane == 0) dnorm[row] = sqrtf(ss) + 1e-8f;
  }
  __syncthreads();
  for (int idx = tid; idx < NN * DD; idx += 512) {
    int row = idx >> 6;
    nen[row * 65 + (idx & 63)] /= dnorm[row];
  }
  // ---- prep all 100 rows (h, nd, kk, q); write h for own quarter only
  for (int row = wid; row < NN; row += 8) {
    float hs = bs[lane], hd = bd[lane], ed = lb[lane];
#pragma unroll
    for (int f = 0; f < FD; ++f) {
      float xv = sx[row][f];
      hs = fmaf(xv, Ws[f * DD + lane], hs);
      hd = fmaf(xv, Wd[f * DD + lane], hd);
      ed = fmaf(xv, lW[f * DD + lane], ed);
    }
    int gi = base + row;
    if (row / 25 == q) {  // each row stored by exactly one sibling block
      h_s[gi * DD + lane] = hs;
      h_d[gi * DD + lane] = hd;
    }
    float ss = ed * ed;
    for (int off = 32; off > 0; off >>= 1) ss += __shfl_xor(ss, off, 64);
    snd[row * 65 + lane] = ed / (sqrtf(ss) + 1e-8f);
    float em = ne[row * DD + lane];
    float ks = hs + em, kd = hd + em;
    float qs = ks * as_[lane], kks = ks * as_[DD + lane];
    float qd = kd * ad[lane], kkd = kd * ad[DD + lane];
    for (int off = 32; off > 0; off >>= 1) {
      qs += __shfl_xor(qs, off, 64);
      kks += __shfl_xor(kks, off, 64);
      qd += __shfl_xor(qd, off, 64);
      kkd += __shfl_xor(kkd, off, 64);
    }
    if (lane == 0) {
      sq_s[row] = qs; skk_s[row] = kks; sq_d[row] = qd; skk_d[row] = kkd;
    }
  }
  __syncthreads();
  // ---- edge decisions + score matrices for own 25 rows x 100 cols
  for (int p = tid; p < 25 * NN; p += 512) {
    int lr = p / NN, c = p - lr * NN;
    int r = q * 25 + lr;   // sample-local row
    int i = base + r;      // global row
    // static (same 100x100 gumbels for every sample, as ref's tile)
    float sim = 0.0f;
#pragma unroll
    for (int k = 0; k < DD; ++k)
      sim = fmaf(nen[r * 65 + k], nen[c * 65 + k], sim);
    uint32_t ps = (uint32_t)(r * NN + c);
    float g0 = gumbel_noise(k1a, k1b, 2u * ps);
    float g1 = gumbel_noise(k1a, k1b, 2u * ps + 1u);
    bool edge = (sim + g0 >= 1.0f - sim + g1) || (r == c);
    float es = -9e15f;
    if (edge) {
      float v = sq_s[r] + skk_s[c];
      es = (v >= 0.0f) ? v : 0.2f * v;
    }
    esM[i * NN + c] = es;
    // dynamic
    float sd = 0.0f;
#pragma unroll
    for (int k = 0; k < DD; ++k)
      sd = fmaf(snd[r * 65 + k], snd[c * 65 + k], sd);
    uint32_t cd = ((uint32_t)i * 3200u + (uint32_t)(base + c)) * 2u;
    float h0 = gumbel_noise(k2a, k2b, cd);
    float h1 = gumbel_noise(k2a, k2b, cd + 1u);
    float edv = -9e15f;
    if (sd + h0 >= 1.0f - sd + h1) {
      float v = sq_d[r] + skk_d[c];
      edv = (v >= 0.0f) ? v : 0.2f * v;
    }
    edM[i * NN + c] = edv;
  }
}

// ---------------- K2: softmax + PV + BN partials (4 rows/block) ----------------
__global__ __launch_bounds__(256) void k_attn(
    const float* __restrict__ h_s, const float* __restrict__ h_d,
    const float* __restrict__ esM, const float* __restrict__ edM,
    const float* __restrict__ ne, float* __restrict__ o,
    float* __restrict__ gstat) {
  __shared__ float att[4][2][NN];
  int tid = threadIdx.x, wid = tid >> 6, lane = tid & 63;
  int blk = blockIdx.x;
  int i = blk * 4 + wid;
  int b = i / NN, r = i - b * NN;
  int base = b * NN;
  int j0 = lane, j1 = lane + 64;
  bool v1 = (j1 < NN);
  // load precomputed scores (coalesced)
  float es0 = esM[i * NN + j0];
  float es1 = v1 ? esM[i * NN + j1] : -9e15f;
  float ed0 = edM[i * NN + j0];
  float ed1 = v1 ? edM[i * NN + j1] : -9e15f;
  // wave softmax, static (identical to r2)
  float ms = fmaxf(es0, es1);
  for (int off = 32; off > 0; off >>= 1) ms = fmaxf(ms, __shfl_xor(ms, off, 64));
  float ws0 = expf(es0 - ms);
  float ws1 = v1 ? expf(es1 - ms) : 0.0f;
  float Ss = ws0 + ws1;
  for (int off = 32; off > 0; off >>= 1) Ss += __shfl_xor(Ss, off, 64);
  att[wid][0][j0] = ws0 / Ss;
  if (v1) att[wid][0][j1] = ws1 / Ss;
  // wave softmax, dynamic
  float md = fmaxf(ed0, ed1);
  for (int off = 32; off > 0; off >>= 1) md = fmaxf(md, __shfl_xor(md, off, 64));
  float wd0 = expf(ed0 - md);
  float wd1 = v1 ? expf(ed1 - md) : 0.0f;
  float Sd = wd0 + wd1;
  for (int off = 32; off > 0; off >>= 1) Sd += __shfl_xor(Sd, off, 64);
  att[wid][1][j0] = wd0 / Sd;
  if (v1) att[wid][1][j1] = wd1 / Sd;
  // PV: lane = channel; h rows from L2 (identical accumulation to r2)
  float hs = 0.0f, hd2 = 0.0f;
  const float* hsp = h_s + base * DD + lane;
  const float* hdp = h_d + base * DD + lane;
#pragma unroll 4
  for (int j = 0; j < NN; ++j) {
    hs = fmaf(att[wid][0][j], hsp[j * DD], hs);
    hd2 = fmaf(att[wid][1][j], hdp[j * DD], hd2);
  }
  float eS = (hs > 0.0f) ? hs : expm1f(hs);
  float eD = (hd2 > 0.0f) ? hd2 : expm1f(hd2);
  float ov = (eS + 0.01f * eD) * ne[r * DD + lane];
  o[i * DD + lane] = ov;
  // BN partials: block reduce (reuse att), 128 device-scope atomics
  __syncthreads();
  att[wid][0][lane] = ov;
  att[wid][1][lane] = ov * ov;
  __syncthreads();
  if (wid == 0) {
    float s = att[0][0][lane] + att[1][0][lane] + att[2][0][lane] + att[3][0][lane];
    unsafeAtomicAdd(&gstat[lane], s);
  } else if (wid == 1) {
    float s = att[0][1][lane] + att[1][1][lane] + att[2][1][lane] + att[3][1][lane];
    unsafeAtomicAdd(&gstat[64 + lane], s);
  }
}

// ---------------- K3: BN finalize + apply + ReLU + out projection ----------------
__global__ __launch_bounds__(256) void k_final(
    const float* __restrict__ o, const float* __restrict__ gstat,
    const float* __restrict__ gamma, const float* __restrict__ beta,
    const float* __restrict__ outW, const float* __restrict__ outb,
    float* __restrict__ out) {
  int tid = threadIdx.x, wid = tid >> 6, lane = tid & 63;
  int i = blockIdx.x * 4 + wid;
  float m = gstat[lane] * (1.0f / NT);
  float ex2 = gstat[64 + lane] * (1.0f / NT);
  float var = ex2 - m * m;
  float scale = gamma[lane] / sqrtf(var + 1e-5f);
  float xv = o[i * DD + lane];
  float v = (xv - m) * scale + beta[lane];
  v = fmaxf(v, 0.0f);
  float p = v * outW[lane];
  for (int off = 32; off > 0; off >>= 1) p += __shfl_xor(p, off, 64);
  if (lane == 0) out[i] = p + outb[0];
}

extern "C" void kernel_launch(void* const* d_in, const int* in_sizes, int n_in,
                              void* d_out, int out_size, void* d_ws,
                              size_t ws_size, hipStream_t stream) {
  const float* data = (const float*)d_in[0];
  const float* node_emb = (const float*)d_in[1];
  const float* lin_W = (const float*)d_in[2];
  const float* lin_b = (const float*)d_in[3];
  const float* gat_s_W = (const float*)d_in[4];
  const float* gat_s_b = (const float*)d_in[5];
  const float* gat_s_a = (const float*)d_in[6];
  const float* gat_d_W = (const float*)d_in[7];
  const float* gat_d_b = (const float*)d_in[8];
  const float* gat_d_a = (const float*)d_in[9];
  const float* bn_gamma = (const float*)d_in[10];
  const float* bn_beta = (const float*)d_in[11];
  const float* out_W = (const float*)d_in[12];
  const float* out_b = (const float*)d_in[13];
  float* out = (float*)d_out;

  float* ws = (float*)d_ws;
  float* h_s = ws;                  // NT*DD = 204800
  float* h_d = ws + 204800;         // NT*DD
  float* esM = ws + 409600;         // NT*NN = 320000
  float* edM = ws + 729600;         // NT*NN
  float* o = ws + 1049600;          // NT*DD
  float* gstat = ws + 1254400;      // 128 (sum[64], sumsq[64])

  // JAX key(42): partitionable split -> k1=cipher(key,(0,0)), k2=cipher(key,(0,1))
  uint32_t k1a, k1b, k2a, k2b;
  tf2x32(0u, 42u, 0u, 0u, k1a, k1b);
  tf2x32(0u, 42u, 0u, 1u, k2a, k2b);

  k_prep<<<128, 512, 0, stream>>>(data, node_emb, lin_W, lin_b, gat_s_W,
                                  gat_s_b, gat_s_a, gat_d_W, gat_d_b, gat_d_a,
                                  h_s, h_d, esM, edM, gstat, k1a, k1b, k2a,
                                  k2b);
  k_attn<<<800, 256, 0, stream>>>(h_s, h_d, esM, edM, node_emb, o, gstat);
  k_final<<<800, 256, 0, stream>>>(o, gstat, bn_gamma, bn_beta, out_W, out_b,
                                   out);
}

// Round 7
// 135.261 us; speedup vs baseline: 1.4015x; 1.0811x over previous
//
#include <hip/hip_runtime.h>
#include <cstdint>

// Problem constants (fixed by reference)
#define NT 3200   // B*N
#define NN 100    // N
#define FD 10     // F_IN
#define DD 64     // D

// ---------------- threefry2x32 (JAX PRNG), host+device ----------------
__host__ __device__ inline void tf2x32(uint32_t ks0, uint32_t ks1, uint32_t x0,
                                       uint32_t x1, uint32_t& o0, uint32_t& o1) {
  uint32_t ks2 = ks0 ^ ks1 ^ 0x1BD11BDAu;
  x0 += ks0; x1 += ks1;
#define TF_RND(r) { x0 += x1; x1 = (x1 << (r)) | (x1 >> (32 - (r))); x1 ^= x0; }
  TF_RND(13) TF_RND(15) TF_RND(26) TF_RND(6)
  x0 += ks1; x1 += ks2 + 1u;
  TF_RND(17) TF_RND(29) TF_RND(16) TF_RND(24)
  x0 += ks2; x1 += ks0 + 2u;
  TF_RND(13) TF_RND(15) TF_RND(26) TF_RND(6)
  x0 += ks0; x1 += ks1 + 3u;
  TF_RND(17) TF_RND(29) TF_RND(16) TF_RND(24)
  x0 += ks1; x1 += ks2 + 4u;
  TF_RND(13) TF_RND(15) TF_RND(26) TF_RND(6)
  x0 += ks2; x1 += ks0 + 5u;
#undef TF_RND
  o0 = x0; o1 = x1;
}

// JAX partitionable random_bits(32) for counter (0, cnt); uniform(1e-20,1); gumbel.
__device__ inline float gumbel_noise(uint32_t ka, uint32_t kb, uint32_t cnt) {
  uint32_t o0, o1;
  tf2x32(ka, kb, 0u, cnt, o0, o1);
  uint32_t bits = o0 ^ o1;
  float u = __uint_as_float((bits >> 9) | 0x3F800000u) - 1.0f;
  u = fmaxf(u, 1e-20f);
  return -logf(-logf(u));
}

// ---------------- K1: per-row prep (blocks 0..799) + static adj (800..839) ----
__global__ __launch_bounds__(256) void k_prep_adj(
    const float* __restrict__ x, const float* __restrict__ ne,
    const float* __restrict__ lW, const float* __restrict__ lb,
    const float* __restrict__ Ws, const float* __restrict__ bs,
    const float* __restrict__ as_, const float* __restrict__ Wd,
    const float* __restrict__ bd, const float* __restrict__ ad,
    float* __restrict__ h_s, float* __restrict__ h_d, float* __restrict__ nd,
    float* __restrict__ q_s, float* __restrict__ kk_s, float* __restrict__ q_d,
    float* __restrict__ kk_d, float* __restrict__ adjS,
    float* __restrict__ gstat, uint32_t k1a, uint32_t k1b) {
  __shared__ float sne[NN * 65];
  __shared__ float dnorm[NN];
  int tid = threadIdx.x, wid = tid >> 6, lane = tid & 63;
  int blk = blockIdx.x;
  if (blk < 800) {
    // wave-per-row prep: h_s, h_d, normalized dyn-emb, attention projections
    int i = blk * 4 + wid;
    const float* xr = x + i * FD;
    float hs = bs[lane], hd = bd[lane], ed = lb[lane];
#pragma unroll
    for (int f = 0; f < FD; ++f) {
      float xv = xr[f];
      hs = fmaf(xv, Ws[f * DD + lane], hs);
      hd = fmaf(xv, Wd[f * DD + lane], hd);
      ed = fmaf(xv, lW[f * DD + lane], ed);
    }
    h_s[i * DD + lane] = hs;
    h_d[i * DD + lane] = hd;
    float ss = ed * ed;
    for (int off = 32; off > 0; off >>= 1) ss += __shfl_xor(ss, off, 64);
    nd[i * DD + lane] = ed / (sqrtf(ss) + 1e-8f);
    int r = i % NN;
    float em = ne[r * DD + lane];
    float ks = hs + em, kd = hd + em;
    float qs = ks * as_[lane], kks = ks * as_[DD + lane];
    float qd = kd * ad[lane], kkd = kd * ad[DD + lane];
    for (int off = 32; off > 0; off >>= 1) {
      qs += __shfl_xor(qs, off, 64);
      kks += __shfl_xor(kks, off, 64);
      qd += __shfl_xor(qd, off, 64);
      kkd += __shfl_xor(kkd, off, 64);
    }
    if (lane == 0) { q_s[i] = qs; kk_s[i] = kks; q_d[i] = qd; kk_d[i] = kkd; }
  } else {
    if (blk == 800 && tid < 128) gstat[tid] = 0.0f;  // zero BN accumulators
    // static adjacency: stage+normalize node_emb in LDS, 100x100 decisions
    for (int idx = tid; idx < NN * DD; idx += 256)
      sne[(idx >> 6) * 65 + (idx & 63)] = ne[idx];
    __syncthreads();
    for (int row = wid; row < NN; row += 4) {
      float v = sne[row * 65 + lane];
      float ss = v * v;
      for (int off = 32; off > 0; off >>= 1) ss += __shfl_xor(ss, off, 64);
      if (lane == 0) dnorm[row] = sqrtf(ss) + 1e-8f;
    }
    __syncthreads();
    for (int idx = tid; idx < NN * DD; idx += 256) {
      int row = idx >> 6;
      sne[row * 65 + (idx & 63)] /= dnorm[row];
    }
    __syncthreads();
    int p = (blk - 800) * 256 + tid;
    if (p < NN * NN) {
      int r = p / NN, c = p - r * NN;
      float sim = 0.0f;
#pragma unroll
      for (int k = 0; k < DD; ++k)
        sim = fmaf(sne[r * 65 + k], sne[c * 65 + k], sim);
      float g0 = gumbel_noise(k1a, k1b, (uint32_t)(2 * p));
      float g1 = gumbel_noise(k1a, k1b, (uint32_t)(2 * p + 1));
      bool edge = (sim + g0 >= 1.0f - sim + g1) || (r == c);
      adjS[p] = edge ? 1.0f : 0.0f;
    }
  }
}

// ---------------- K2: wave-per-row attention (register softmax, shfl PV) ----
__global__ __launch_bounds__(256) void k_attn(
    const float* __restrict__ h_s, const float* __restrict__ h_d,
    const float* __restrict__ nd, const float* __restrict__ q_s,
    const float* __restrict__ kk_s, const float* __restrict__ q_d,
    const float* __restrict__ kk_d, const float* __restrict__ adjS,
    const float* __restrict__ ne, float* __restrict__ o,
    float* __restrict__ gstat, uint32_t k2a, uint32_t k2b) {
  __shared__ float lnd[NN * 65];     // pad 65 -> conflict-free row access
  __shared__ float sums[2][4][64];   // BN partials
  int tid = threadIdx.x, wid = tid >> 6, lane = tid & 63;
  int blk = blockIdx.x;
  int b = blk / 25, rb = (blk % 25) * 4;
  int base = b * NN;
  // stage normalized dynamic embeddings of this sample (once per 4 rows)
  for (int idx = tid; idx < NN * DD; idx += 256)
    lnd[(idx >> 6) * 65 + (idx & 63)] = nd[base * DD + idx];
  __syncthreads();

  int r = rb + wid;
  int i = base + r;  // == blk*4 + wid
  float sqs = q_s[i], sqd = q_d[i];
  int j0 = lane, j1 = lane + 64;
  bool v1 = (j1 < NN);
  int jj1 = v1 ? j1 : 0;
  // cosine sims vs row r (LDS: broadcast + stride-65)
  float sim0 = 0.0f, sim1 = 0.0f;
  const float* ndr = &lnd[r * 65];
  const float* nj0 = &lnd[j0 * 65];
  const float* nj1 = &lnd[jj1 * 65];
#pragma unroll
  for (int k = 0; k < DD; ++k) {
    float a = ndr[k];
    sim0 = fmaf(a, nj0[k], sim0);
    sim1 = fmaf(a, nj1[k], sim1);
  }
  // static edges (precomputed adjacency)
  float es0 = -9e15f, es1 = -9e15f, ed0 = -9e15f, ed1 = -9e15f;
  if (adjS[r * NN + j0] > 0.0f) {
    float v = sqs + kk_s[base + j0];
    es0 = (v >= 0.0f) ? v : 0.2f * v;
  }
  if (v1 && adjS[r * NN + j1] > 0.0f) {
    float v = sqs + kk_s[base + j1];
    es1 = (v >= 0.0f) ? v : 0.2f * v;
  }
  // dynamic edges (gumbel on the fly)
  {
    uint32_t c0 = ((uint32_t)i * 3200u + (uint32_t)(base + j0)) * 2u;
    float g0 = gumbel_noise(k2a, k2b, c0);
    float g1 = gumbel_noise(k2a, k2b, c0 + 1u);
    if (sim0 + g0 >= 1.0f - sim0 + g1) {
      float v = sqd + kk_d[base + j0];
      ed0 = (v >= 0.0f) ? v : 0.2f * v;
    }
  }
  if (v1) {
    uint32_t c1 = ((uint32_t)i * 3200u + (uint32_t)(base + j1)) * 2u;
    float g0 = gumbel_noise(k2a, k2b, c1);
    float g1 = gumbel_noise(k2a, k2b, c1 + 1u);
    if (sim1 + g0 >= 1.0f - sim1 + g1) {
      float v = sqd + kk_d[base + j1];
      ed1 = (v >= 0.0f) ? v : 0.2f * v;
    }
  }
  // wave softmax, static (registers only)
  float ms = fmaxf(es0, es1);
  for (int off = 32; off > 0; off >>= 1) ms = fmaxf(ms, __shfl_xor(ms, off, 64));
  float ws0 = expf(es0 - ms);
  float ws1 = v1 ? expf(es1 - ms) : 0.0f;
  float Ss = ws0 + ws1;
  for (int off = 32; off > 0; off >>= 1) Ss += __shfl_xor(Ss, off, 64);
  float a0s = ws0 / Ss, a1s = ws1 / Ss;
  // wave softmax, dynamic
  float md = fmaxf(ed0, ed1);
  for (int off = 32; off > 0; off >>= 1) md = fmaxf(md, __shfl_xor(md, off, 64));
  float wd0 = expf(ed0 - md);
  float wd1 = v1 ? expf(ed1 - md) : 0.0f;
  float Sd = wd0 + wd1;
  for (int off = 32; off > 0; off >>= 1) Sd += __shfl_xor(Sd, off, 64);
  float a0d = wd0 / Sd, a1d = wd1 / Sd;
  // PV: lane = channel; att broadcast via shfl, h rows coalesced from L2
  float hs = 0.0f, hd2 = 0.0f;
  const float* hsp = h_s + base * DD + lane;
  const float* hdp = h_d + base * DD + lane;
#pragma unroll 4
  for (int j = 0; j < 64; ++j) {
    hs = fmaf(__shfl(a0s, j, 64), hsp[j * DD], hs);
    hd2 = fmaf(__shfl(a0d, j, 64), hdp[j * DD], hd2);
  }
#pragma unroll 4
  for (int j = 0; j < 36; ++j) {
    hs = fmaf(__shfl(a1s, j, 64), hsp[(j + 64) * DD], hs);
    hd2 = fmaf(__shfl(a1d, j, 64), hdp[(j + 64) * DD], hd2);
  }
  float eS = (hs > 0.0f) ? hs : expm1f(hs);
  float eD = (hd2 > 0.0f) ? hd2 : expm1f(hd2);
  float ov = (eS + 0.01f * eD) * ne[r * DD + lane];
  o[i * DD + lane] = ov;
  // BN partials: block reduce, 128 device-scope atomics
  sums[0][wid][lane] = ov;
  sums[1][wid][lane] = ov * ov;
  __syncthreads();
  if (wid == 0) {
    float s = sums[0][0][lane] + sums[0][1][lane] + sums[0][2][lane] + sums[0][3][lane];
    unsafeAtomicAdd(&gstat[lane], s);
  } else if (wid == 1) {
    float s = sums[1][0][lane] + sums[1][1][lane] + sums[1][2][lane] + sums[1][3][lane];
    unsafeAtomicAdd(&gstat[64 + lane], s);
  }
}

// ---------------- K3: BN finalize + apply + ReLU + out projection ----------------
__global__ __launch_bounds__(256) void k_final(
    const float* __restrict__ o, const float* __restrict__ gstat,
    const float* __restrict__ gamma, const float* __restrict__ beta,
    const float* __restrict__ outW, const float* __restrict__ outb,
    float* __restrict__ out) {
  int tid = threadIdx.x, wid = tid >> 6, lane = tid & 63;
  int i = blockIdx.x * 4 + wid;
  float m = gstat[lane] * (1.0f / NT);
  float ex2 = gstat[64 + lane] * (1.0f / NT);
  float var = ex2 - m * m;
  float scale = gamma[lane] / sqrtf(var + 1e-5f);
  float xv = o[i * DD + lane];
  float v = (xv - m) * scale + beta[lane];
  v = fmaxf(v, 0.0f);
  float p = v * outW[lane];
  for (int off = 32; off > 0; off >>= 1) p += __shfl_xor(p, off, 64);
  if (lane == 0) out[i] = p + outb[0];
}

extern "C" void kernel_launch(void* const* d_in, const int* in_sizes, int n_in,
                              void* d_out, int out_size, void* d_ws,
                              size_t ws_size, hipStream_t stream) {
  const float* data = (const float*)d_in[0];
  const float* node_emb = (const float*)d_in[1];
  const float* lin_W = (const float*)d_in[2];
  const float* lin_b = (const float*)d_in[3];
  const float* gat_s_W = (const float*)d_in[4];
  const float* gat_s_b = (const float*)d_in[5];
  const float* gat_s_a = (const float*)d_in[6];
  const float* gat_d_W = (const float*)d_in[7];
  const float* gat_d_b = (const float*)d_in[8];
  const float* gat_d_a = (const float*)d_in[9];
  const float* bn_gamma = (const float*)d_in[10];
  const float* bn_beta = (const float*)d_in[11];
  const float* out_W = (const float*)d_in[12];
  const float* out_b = (const float*)d_in[13];
  float* out = (float*)d_out;

  float* ws = (float*)d_ws;
  float* h_s = ws;                 // NT*DD
  float* h_d = ws + 204800;        // NT*DD
  float* nd = ws + 409600;         // NT*DD
  float* q_s = ws + 614400;        // NT
  float* kk_s = ws + 617600;       // NT
  float* q_d = ws + 620800;        // NT
  float* kk_d = ws + 624000;       // NT
  float* adjS = ws + 627200;       // NN*NN
  float* o = ws + 637200;          // NT*DD
  float* gstat = ws + 842000;      // 128 (sum[64], sumsq[64])

  // JAX key(42): partitionable split -> k1=cipher(key,(0,0)), k2=cipher(key,(0,1))
  uint32_t k1a, k1b, k2a, k2b;
  tf2x32(0u, 42u, 0u, 0u, k1a, k1b);
  tf2x32(0u, 42u, 0u, 1u, k2a, k2b);

  k_prep_adj<<<840, 256, 0, stream>>>(data, node_emb, lin_W, lin_b, gat_s_W,
                                      gat_s_b, gat_s_a, gat_d_W, gat_d_b,
                                      gat_d_a, h_s, h_d, nd, q_s, kk_s, q_d,
                                      kk_d, adjS, gstat, k1a, k1b);
  k_attn<<<800, 256, 0, stream>>>(h_s, h_d, nd, q_s, kk_s, q_d, kk_d, adjS,
                                  node_emb, o, gstat, k2a, k2b);
  k_final<<<800, 256, 0, stream>>>(o, gstat, bn_gamma, bn_beta, out_W, out_b,
                                   out);
}

// Round 8
// 134.477 us; speedup vs baseline: 1.4097x; 1.0058x over previous
//
#include <hip/hip_runtime.h>
#include <cstdint>

// Problem constants (fixed by reference)
#define NT 3200   // B*N
#define NN 100    // N
#define FD 10     // F_IN
#define DD 64     // D

// ---------------- threefry2x32 (JAX PRNG), host+device ----------------
__host__ __device__ inline void tf2x32(uint32_t ks0, uint32_t ks1, uint32_t x0,
                                       uint32_t x1, uint32_t& o0, uint32_t& o1) {
  uint32_t ks2 = ks0 ^ ks1 ^ 0x1BD11BDAu;
  x0 += ks0; x1 += ks1;
#define TF_RND(r) { x0 += x1; x1 = (x1 << (r)) | (x1 >> (32 - (r))); x1 ^= x0; }
  TF_RND(13) TF_RND(15) TF_RND(26) TF_RND(6)
  x0 += ks1; x1 += ks2 + 1u;
  TF_RND(17) TF_RND(29) TF_RND(16) TF_RND(24)
  x0 += ks2; x1 += ks0 + 2u;
  TF_RND(13) TF_RND(15) TF_RND(26) TF_RND(6)
  x0 += ks0; x1 += ks1 + 3u;
  TF_RND(17) TF_RND(29) TF_RND(16) TF_RND(24)
  x0 += ks1; x1 += ks2 + 4u;
  TF_RND(13) TF_RND(15) TF_RND(26) TF_RND(6)
  x0 += ks2; x1 += ks0 + 5u;
#undef TF_RND
  o0 = x0; o1 = x1;
}

// JAX partitionable random_bits(32) for counter (0, cnt); uniform(1e-20,1); gumbel.
__device__ inline float gumbel_noise(uint32_t ka, uint32_t kb, uint32_t cnt) {
  uint32_t o0, o1;
  tf2x32(ka, kb, 0u, cnt, o0, o1);
  uint32_t bits = o0 ^ o1;
  float u = __uint_as_float((bits >> 9) | 0x3F800000u) - 1.0f;
  u = fmaxf(u, 1e-20f);
  return -logf(-logf(u));
}

// ---------------- K1: per-row prep (blocks 0..799) + static adj (800..839) ----
__global__ __launch_bounds__(256) void k_prep_adj(
    const float* __restrict__ x, const float* __restrict__ ne,
    const float* __restrict__ lW, const float* __restrict__ lb,
    const float* __restrict__ Ws, const float* __restrict__ bs,
    const float* __restrict__ as_, const float* __restrict__ Wd,
    const float* __restrict__ bd, const float* __restrict__ ad,
    float* __restrict__ h_s, float* __restrict__ h_d, float* __restrict__ nd,
    float* __restrict__ q_s, float* __restrict__ kk_s, float* __restrict__ q_d,
    float* __restrict__ kk_d, float* __restrict__ adjS,
    float* __restrict__ gstat, uint32_t k1a, uint32_t k1b) {
  __shared__ float sne[NN * 65];
  __shared__ float dnorm[NN];
  int tid = threadIdx.x, wid = tid >> 6, lane = tid & 63;
  int blk = blockIdx.x;
  if (blk < 800) {
    // wave-per-row prep: h_s, h_d, normalized dyn-emb, attention projections
    int i = blk * 4 + wid;
    const float* xr = x + i * FD;
    float hs = bs[lane], hd = bd[lane], ed = lb[lane];
#pragma unroll
    for (int f = 0; f < FD; ++f) {
      float xv = xr[f];
      hs = fmaf(xv, Ws[f * DD + lane], hs);
      hd = fmaf(xv, Wd[f * DD + lane], hd);
      ed = fmaf(xv, lW[f * DD + lane], ed);
    }
    h_s[i * DD + lane] = hs;
    h_d[i * DD + lane] = hd;
    float ss = ed * ed;
    for (int off = 32; off > 0; off >>= 1) ss += __shfl_xor(ss, off, 64);
    nd[i * DD + lane] = ed / (sqrtf(ss) + 1e-8f);
    int r = i % NN;
    float em = ne[r * DD + lane];
    float ks = hs + em, kd = hd + em;
    float qs = ks * as_[lane], kks = ks * as_[DD + lane];
    float qd = kd * ad[lane], kkd = kd * ad[DD + lane];
    for (int off = 32; off > 0; off >>= 1) {
      qs += __shfl_xor(qs, off, 64);
      kks += __shfl_xor(kks, off, 64);
      qd += __shfl_xor(qd, off, 64);
      kkd += __shfl_xor(kkd, off, 64);
    }
    if (lane == 0) { q_s[i] = qs; kk_s[i] = kks; q_d[i] = qd; kk_d[i] = kkd; }
  } else {
    if (blk == 800 && tid < 128) gstat[tid] = 0.0f;  // zero BN accumulators
    // static adjacency: stage+normalize node_emb in LDS, 100x100 decisions
    {
      const float4* nev = (const float4*)ne;
      for (int idx = tid; idx < NN * DD / 4; idx += 256) {
        float4 v = nev[idx];
        int row = idx >> 4, c4 = (idx & 15) * 4;
        float* dst = &sne[row * 65 + c4];
        dst[0] = v.x; dst[1] = v.y; dst[2] = v.z; dst[3] = v.w;
      }
    }
    __syncthreads();
    for (int row = wid; row < NN; row += 4) {
      float v = sne[row * 65 + lane];
      float ss = v * v;
      for (int off = 32; off > 0; off >>= 1) ss += __shfl_xor(ss, off, 64);
      if (lane == 0) dnorm[row] = sqrtf(ss) + 1e-8f;
    }
    __syncthreads();
    for (int idx = tid; idx < NN * DD; idx += 256) {
      int row = idx >> 6;
      sne[row * 65 + (idx & 63)] /= dnorm[row];
    }
    __syncthreads();
    int p = (blk - 800) * 256 + tid;
    if (p < NN * NN) {
      int r = p / NN, c = p - r * NN;
      float sim = 0.0f;
#pragma unroll
      for (int k = 0; k < DD; ++k)
        sim = fmaf(sne[r * 65 + k], sne[c * 65 + k], sim);
      float g0 = gumbel_noise(k1a, k1b, (uint32_t)(2 * p));
      float g1 = gumbel_noise(k1a, k1b, (uint32_t)(2 * p + 1));
      bool edge = (sim + g0 >= 1.0f - sim + g1) || (r == c);
      adjS[p] = edge ? 1.0f : 0.0f;
    }
  }
}

// ---------------- K2: wave-per-row attention (register softmax, LDS-att PV) ----
__global__ __launch_bounds__(256) void k_attn(
    const float* __restrict__ h_s, const float* __restrict__ h_d,
    const float* __restrict__ nd, const float* __restrict__ q_s,
    const float* __restrict__ kk_s, const float* __restrict__ q_d,
    const float* __restrict__ kk_d, const float* __restrict__ adjS,
    const float* __restrict__ ne, float* __restrict__ o,
    float* __restrict__ gstat, uint32_t k2a, uint32_t k2b) {
  __shared__ float lnd[NN * 65];   // pad 65 -> conflict-free row access
  __shared__ float att[4][2][NN];  // per-wave attention rows; reused for stats
  int tid = threadIdx.x, wid = tid >> 6, lane = tid & 63;
  int blk = blockIdx.x;
  int b = blk / 25, rb = (blk % 25) * 4;
  int base = b * NN;
  // stage normalized dynamic embeddings (float4 global loads, scalar LDS writes)
  {
    const float4* ndv = (const float4*)(nd + base * DD);
    for (int idx = tid; idx < NN * DD / 4; idx += 256) {
      float4 v = ndv[idx];
      int row = idx >> 4, c4 = (idx & 15) * 4;
      float* dst = &lnd[row * 65 + c4];
      dst[0] = v.x; dst[1] = v.y; dst[2] = v.z; dst[3] = v.w;
    }
  }
  __syncthreads();

  int r = rb + wid;
  int i = base + r;  // == blk*4 + wid
  float sqs = q_s[i], sqd = q_d[i];
  int j0 = lane, j1 = lane + 64;
  bool v1 = (j1 < NN);
  int jj1 = v1 ? j1 : 0;
  // cosine sims vs row r (LDS: broadcast + stride-65)
  float sim0 = 0.0f, sim1 = 0.0f;
  const float* ndr = &lnd[r * 65];
  const float* nj0 = &lnd[j0 * 65];
  const float* nj1 = &lnd[jj1 * 65];
#pragma unroll
  for (int k = 0; k < DD; ++k) {
    float a = ndr[k];
    sim0 = fmaf(a, nj0[k], sim0);
    sim1 = fmaf(a, nj1[k], sim1);
  }
  // static edges (precomputed adjacency)
  float es0 = -9e15f, es1 = -9e15f, ed0 = -9e15f, ed1 = -9e15f;
  if (adjS[r * NN + j0] > 0.0f) {
    float v = sqs + kk_s[base + j0];
    es0 = (v >= 0.0f) ? v : 0.2f * v;
  }
  if (v1 && adjS[r * NN + j1] > 0.0f) {
    float v = sqs + kk_s[base + j1];
    es1 = (v >= 0.0f) ? v : 0.2f * v;
  }
  // dynamic edges (gumbel on the fly)
  {
    uint32_t c0 = ((uint32_t)i * 3200u + (uint32_t)(base + j0)) * 2u;
    float g0 = gumbel_noise(k2a, k2b, c0);
    float g1 = gumbel_noise(k2a, k2b, c0 + 1u);
    if (sim0 + g0 >= 1.0f - sim0 + g1) {
      float v = sqd + kk_d[base + j0];
      ed0 = (v >= 0.0f) ? v : 0.2f * v;
    }
  }
  if (v1) {
    uint32_t c1 = ((uint32_t)i * 3200u + (uint32_t)(base + j1)) * 2u;
    float g0 = gumbel_noise(k2a, k2b, c1);
    float g1 = gumbel_noise(k2a, k2b, c1 + 1u);
    if (sim1 + g0 >= 1.0f - sim1 + g1) {
      float v = sqd + kk_d[base + j1];
      ed1 = (v >= 0.0f) ? v : 0.2f * v;
    }
  }
  // wave softmax, static (registers only)
  float ms = fmaxf(es0, es1);
  for (int off = 32; off > 0; off >>= 1) ms = fmaxf(ms, __shfl_xor(ms, off, 64));
  float ws0 = expf(es0 - ms);
  float ws1 = v1 ? expf(es1 - ms) : 0.0f;
  float Ss = ws0 + ws1;
  for (int off = 32; off > 0; off >>= 1) Ss += __shfl_xor(Ss, off, 64);
  att[wid][0][j0] = ws0 / Ss;
  if (v1) att[wid][0][j1] = ws1 / Ss;
  // wave softmax, dynamic
  float md = fmaxf(ed0, ed1);
  for (int off = 32; off > 0; off >>= 1) md = fmaxf(md, __shfl_xor(md, off, 64));
  float wd0 = expf(ed0 - md);
  float wd1 = v1 ? expf(ed1 - md) : 0.0f;
  float Sd = wd0 + wd1;
  for (int off = 32; off > 0; off >>= 1) Sd += __shfl_xor(Sd, off, 64);
  att[wid][1][j0] = wd0 / Sd;
  if (v1) att[wid][1][j1] = wd1 / Sd;
  // PV: lane = channel; att via wave-uniform LDS broadcast (no bpermute),
  // h rows coalesced from L2. Identical accumulation order to r2.
  float hs = 0.0f, hd2 = 0.0f;
  const float* hsp = h_s + base * DD + lane;
  const float* hdp = h_d + base * DD + lane;
#pragma unroll 4
  for (int j = 0; j < NN; ++j) {
    hs = fmaf(att[wid][0][j], hsp[j * DD], hs);
    hd2 = fmaf(att[wid][1][j], hdp[j * DD], hd2);
  }
  float eS = (hs > 0.0f) ? hs : expm1f(hs);
  float eD = (hd2 > 0.0f) ? hd2 : expm1f(hd2);
  float ov = (eS + 0.01f * eD) * ne[r * DD + lane];
  o[i * DD + lane] = ov;
  // BN partials: block reduce (reuse att), 128 device-scope atomics
  __syncthreads();
  att[wid][0][lane] = ov;
  att[wid][1][lane] = ov * ov;
  __syncthreads();
  if (wid == 0) {
    float s = att[0][0][lane] + att[1][0][lane] + att[2][0][lane] + att[3][0][lane];
    unsafeAtomicAdd(&gstat[lane], s);
  } else if (wid == 1) {
    float s = att[0][1][lane] + att[1][1][lane] + att[2][1][lane] + att[3][1][lane];
    unsafeAtomicAdd(&gstat[64 + lane], s);
  }
}

// ---------------- K3: BN finalize + apply + ReLU + out projection ----------------
__global__ __launch_bounds__(256) void k_final(
    const float* __restrict__ o, const float* __restrict__ gstat,
    const float* __restrict__ gamma, const float* __restrict__ beta,
    const float* __restrict__ outW, const float* __restrict__ outb,
    float* __restrict__ out) {
  int tid = threadIdx.x, wid = tid >> 6, lane = tid & 63;
  int i = blockIdx.x * 4 + wid;
  float m = gstat[lane] * (1.0f / NT);
  float ex2 = gstat[64 + lane] * (1.0f / NT);
  float var = ex2 - m * m;
  float scale = gamma[lane] / sqrtf(var + 1e-5f);
  float xv = o[i * DD + lane];
  float v = (xv - m) * scale + beta[lane];
  v = fmaxf(v, 0.0f);
  float p = v * outW[lane];
  for (int off = 32; off > 0; off >>= 1) p += __shfl_xor(p, off, 64);
  if (lane == 0) out[i] = p + outb[0];
}

extern "C" void kernel_launch(void* const* d_in, const int* in_sizes, int n_in,
                              void* d_out, int out_size, void* d_ws,
                              size_t ws_size, hipStream_t stream) {
  const float* data = (const float*)d_in[0];
  const float* node_emb = (const float*)d_in[1];
  const float* lin_W = (const float*)d_in[2];
  const float* lin_b = (const float*)d_in[3];
  const float* gat_s_W = (const float*)d_in[4];
  const float* gat_s_b = (const float*)d_in[5];
  const float* gat_s_a = (const float*)d_in[6];
  const float* gat_d_W = (const float*)d_in[7];
  const float* gat_d_b = (const float*)d_in[8];
  const float* gat_d_a = (const float*)d_in[9];
  const float* bn_gamma = (const float*)d_in[10];
  const float* bn_beta = (const float*)d_in[11];
  const float* out_W = (const float*)d_in[12];
  const float* out_b = (const float*)d_in[13];
  float* out = (float*)d_out;

  float* ws = (float*)d_ws;
  float* h_s = ws;                 // NT*DD
  float* h_d = ws + 204800;        // NT*DD
  float* nd = ws + 409600;         // NT*DD
  float* q_s = ws + 614400;        // NT
  float* kk_s = ws + 617600;       // NT
  float* q_d = ws + 620800;        // NT
  float* kk_d = ws + 624000;       // NT
  float* adjS = ws + 627200;       // NN*NN
  float* o = ws + 637200;          // NT*DD
  float* gstat = ws + 842000;      // 128 (sum[64], sumsq[64])

  // JAX key(42): partitionable split -> k1=cipher(key,(0,0)), k2=cipher(key,(0,1))
  uint32_t k1a, k1b, k2a, k2b;
  tf2x32(0u, 42u, 0u, 0u, k1a, k1b);
  tf2x32(0u, 42u, 0u, 1u, k2a, k2b);

  k_prep_adj<<<840, 256, 0, stream>>>(data, node_emb, lin_W, lin_b, gat_s_W,
                                      gat_s_b, gat_s_a, gat_d_W, gat_d_b,
                                      gat_d_a, h_s, h_d, nd, q_s, kk_s, q_d,
                                      kk_d, adjS, gstat, k1a, k1b);
  k_attn<<<800, 256, 0, stream>>>(h_s, h_d, nd, q_s, kk_s, q_d, kk_d, adjS,
                                  node_emb, o, gstat, k2a, k2b);
  k_final<<<800, 256, 0, stream>>>(o, gstat, bn_gamma, bn_beta, out_W, out_b,
                                   out);
}

// Round 9
// 132.366 us; speedup vs baseline: 1.4322x; 1.0160x over previous
//
#include <hip/hip_runtime.h>
#include <cstdint>

// Problem constants (fixed by reference)
#define NT 3200   // B*N
#define NN 100    // N
#define FD 10     // F_IN
#define DD 64     // D

// ---------------- threefry2x32 (JAX PRNG), host+device ----------------
__host__ __device__ inline void tf2x32(uint32_t ks0, uint32_t ks1, uint32_t x0,
                                       uint32_t x1, uint32_t& o0, uint32_t& o1) {
  uint32_t ks2 = ks0 ^ ks1 ^ 0x1BD11BDAu;
  x0 += ks0; x1 += ks1;
#define TF_RND(r) { x0 += x1; x1 = (x1 << (r)) | (x1 >> (32 - (r))); x1 ^= x0; }
  TF_RND(13) TF_RND(15) TF_RND(26) TF_RND(6)
  x0 += ks1; x1 += ks2 + 1u;
  TF_RND(17) TF_RND(29) TF_RND(16) TF_RND(24)
  x0 += ks2; x1 += ks0 + 2u;
  TF_RND(13) TF_RND(15) TF_RND(26) TF_RND(6)
  x0 += ks0; x1 += ks1 + 3u;
  TF_RND(17) TF_RND(29) TF_RND(16) TF_RND(24)
  x0 += ks1; x1 += ks2 + 4u;
  TF_RND(13) TF_RND(15) TF_RND(26) TF_RND(6)
  x0 += ks2; x1 += ks0 + 5u;
#undef TF_RND
  o0 = x0; o1 = x1;
}

// JAX partitionable random_bits(32) for counter (0, cnt); uniform(1e-20,1); gumbel.
__device__ inline float gumbel_noise(uint32_t ka, uint32_t kb, uint32_t cnt) {
  uint32_t o0, o1;
  tf2x32(ka, kb, 0u, cnt, o0, o1);
  uint32_t bits = o0 ^ o1;
  float u = __uint_as_float((bits >> 9) | 0x3F800000u) - 1.0f;
  u = fmaxf(u, 1e-20f);
  return -logf(-logf(u));
}

// ---------------- K1: per-row prep (blocks 0..799) + static adj (800..839) ----
__global__ __launch_bounds__(256) void k_prep_adj(
    const float* __restrict__ x, const float* __restrict__ ne,
    const float* __restrict__ lW, const float* __restrict__ lb,
    const float* __restrict__ Ws, const float* __restrict__ bs,
    const float* __restrict__ as_, const float* __restrict__ Wd,
    const float* __restrict__ bd, const float* __restrict__ ad,
    float* __restrict__ h_s, float* __restrict__ h_d, float* __restrict__ nd,
    float* __restrict__ q_s, float* __restrict__ kk_s, float* __restrict__ q_d,
    float* __restrict__ kk_d, float* __restrict__ adjS,
    float* __restrict__ gstat, uint32_t k1a, uint32_t k1b) {
  __shared__ float sne[NN * 65];
  __shared__ float dnorm[NN];
  int tid = threadIdx.x, wid = tid >> 6, lane = tid & 63;
  int blk = blockIdx.x;
  if (blk < 800) {
    // wave-per-row prep: h_s, h_d, normalized dyn-emb, attention projections
    int i = blk * 4 + wid;
    const float* xr = x + i * FD;
    float hs = bs[lane], hd = bd[lane], ed = lb[lane];
#pragma unroll
    for (int f = 0; f < FD; ++f) {
      float xv = xr[f];
      hs = fmaf(xv, Ws[f * DD + lane], hs);
      hd = fmaf(xv, Wd[f * DD + lane], hd);
      ed = fmaf(xv, lW[f * DD + lane], ed);
    }
    h_s[i * DD + lane] = hs;
    h_d[i * DD + lane] = hd;
    float ss = ed * ed;
    for (int off = 32; off > 0; off >>= 1) ss += __shfl_xor(ss, off, 64);
    nd[i * DD + lane] = ed / (sqrtf(ss) + 1e-8f);
    int r = i % NN;
    float em = ne[r * DD + lane];
    float ks = hs + em, kd = hd + em;
    float qs = ks * as_[lane], kks = ks * as_[DD + lane];
    float qd = kd * ad[lane], kkd = kd * ad[DD + lane];
    for (int off = 32; off > 0; off >>= 1) {
      qs += __shfl_xor(qs, off, 64);
      kks += __shfl_xor(kks, off, 64);
      qd += __shfl_xor(qd, off, 64);
      kkd += __shfl_xor(kkd, off, 64);
    }
    if (lane == 0) { q_s[i] = qs; kk_s[i] = kks; q_d[i] = qd; kk_d[i] = kkd; }
  } else {
    if (blk == 800 && tid < 128) gstat[tid] = 0.0f;  // zero BN accumulators
    // static adjacency: stage+normalize node_emb in LDS, 100x100 decisions
    {
      const float4* nev = (const float4*)ne;
      for (int idx = tid; idx < NN * DD / 4; idx += 256) {
        float4 v = nev[idx];
        int row = idx >> 4, c4 = (idx & 15) * 4;
        float* dst = &sne[row * 65 + c4];
        dst[0] = v.x; dst[1] = v.y; dst[2] = v.z; dst[3] = v.w;
      }
    }
    __syncthreads();
    for (int row = wid; row < NN; row += 4) {
      float v = sne[row * 65 + lane];
      float ss = v * v;
      for (int off = 32; off > 0; off >>= 1) ss += __shfl_xor(ss, off, 64);
      if (lane == 0) dnorm[row] = sqrtf(ss) + 1e-8f;
    }
    __syncthreads();
    for (int idx = tid; idx < NN * DD; idx += 256) {
      int row = idx >> 6;
      sne[row * 65 + (idx & 63)] /= dnorm[row];
    }
    __syncthreads();
    int p = (blk - 800) * 256 + tid;
    if (p < NN * NN) {
      int r = p / NN, c = p - r * NN;
      float sim = 0.0f;
#pragma unroll
      for (int k = 0; k < DD; ++k)
        sim = fmaf(sne[r * 65 + k], sne[c * 65 + k], sim);
      float g0 = gumbel_noise(k1a, k1b, (uint32_t)(2 * p));
      float g1 = gumbel_noise(k1a, k1b, (uint32_t)(2 * p + 1));
      bool edge = (sim + g0 >= 1.0f - sim + g1) || (r == c);
      adjS[p] = edge ? 1.0f : 0.0f;
    }
  }
}

// ---------------- K2: wave-per-row attention (LDS-resident PV) ----------------
__global__ __launch_bounds__(256) void k_attn(
    const float* __restrict__ h_s, const float* __restrict__ h_d,
    const float* __restrict__ nd, const float* __restrict__ q_s,
    const float* __restrict__ kk_s, const float* __restrict__ q_d,
    const float* __restrict__ kk_d, const float* __restrict__ adjS,
    const float* __restrict__ ne, float* __restrict__ o,
    float* __restrict__ gstat, uint32_t k2a, uint32_t k2b) {
  __shared__ float bufA[NN * 65];  // nd during sims, then h_d for PV
  __shared__ float bufB[NN * 65];  // h_s (staged early; loads overlap sims/RNG)
  __shared__ float att[4][2][NN];  // per-wave attention rows; reused for stats
  int tid = threadIdx.x, wid = tid >> 6, lane = tid & 63;
  int blk = blockIdx.x;
  int b = blk / 25, rb = (blk % 25) * 4;
  int base = b * NN;
  // stage nd -> bufA and h_s -> bufB (independent; float4 global loads)
  {
    const float4* ndv = (const float4*)(nd + base * DD);
    const float4* hsv = (const float4*)(h_s + base * DD);
    for (int idx = tid; idx < NN * DD / 4; idx += 256) {
      float4 v = ndv[idx];
      float4 w = hsv[idx];
      int row = idx >> 4, c4 = (idx & 15) * 4;
      float* dA = &bufA[row * 65 + c4];
      float* dB = &bufB[row * 65 + c4];
      dA[0] = v.x; dA[1] = v.y; dA[2] = v.z; dA[3] = v.w;
      dB[0] = w.x; dB[1] = w.y; dB[2] = w.z; dB[3] = w.w;
    }
  }
  __syncthreads();

  int r = rb + wid;
  int i = base + r;  // == blk*4 + wid
  float sqs = q_s[i], sqd = q_d[i];
  int j0 = lane, j1 = lane + 64;
  bool v1 = (j1 < NN);
  int jj1 = v1 ? j1 : 0;
  // cosine sims vs row r (LDS: broadcast + stride-65)
  float sim0 = 0.0f, sim1 = 0.0f;
  const float* ndr = &bufA[r * 65];
  const float* nj0 = &bufA[j0 * 65];
  const float* nj1 = &bufA[jj1 * 65];
#pragma unroll
  for (int k = 0; k < DD; ++k) {
    float a = ndr[k];
    sim0 = fmaf(a, nj0[k], sim0);
    sim1 = fmaf(a, nj1[k], sim1);
  }
  // static edges (precomputed adjacency)
  float es0 = -9e15f, es1 = -9e15f, ed0 = -9e15f, ed1 = -9e15f;
  if (adjS[r * NN + j0] > 0.0f) {
    float v = sqs + kk_s[base + j0];
    es0 = (v >= 0.0f) ? v : 0.2f * v;
  }
  if (v1 && adjS[r * NN + j1] > 0.0f) {
    float v = sqs + kk_s[base + j1];
    es1 = (v >= 0.0f) ? v : 0.2f * v;
  }
  // dynamic edges (gumbel on the fly)
  {
    uint32_t c0 = ((uint32_t)i * 3200u + (uint32_t)(base + j0)) * 2u;
    float g0 = gumbel_noise(k2a, k2b, c0);
    float g1 = gumbel_noise(k2a, k2b, c0 + 1u);
    if (sim0 + g0 >= 1.0f - sim0 + g1) {
      float v = sqd + kk_d[base + j0];
      ed0 = (v >= 0.0f) ? v : 0.2f * v;
    }
  }
  if (v1) {
    uint32_t c1 = ((uint32_t)i * 3200u + (uint32_t)(base + j1)) * 2u;
    float g0 = gumbel_noise(k2a, k2b, c1);
    float g1 = gumbel_noise(k2a, k2b, c1 + 1u);
    if (sim1 + g0 >= 1.0f - sim1 + g1) {
      float v = sqd + kk_d[base + j1];
      ed1 = (v >= 0.0f) ? v : 0.2f * v;
    }
  }
  // wave softmax, static (registers only)
  float ms = fmaxf(es0, es1);
  for (int off = 32; off > 0; off >>= 1) ms = fmaxf(ms, __shfl_xor(ms, off, 64));
  float ws0 = expf(es0 - ms);
  float ws1 = v1 ? expf(es1 - ms) : 0.0f;
  float Ss = ws0 + ws1;
  for (int off = 32; off > 0; off >>= 1) Ss += __shfl_xor(Ss, off, 64);
  att[wid][0][j0] = ws0 / Ss;
  if (v1) att[wid][0][j1] = ws1 / Ss;
  // wave softmax, dynamic
  float md = fmaxf(ed0, ed1);
  for (int off = 32; off > 0; off >>= 1) md = fmaxf(md, __shfl_xor(md, off, 64));
  float wd0 = expf(ed0 - md);
  float wd1 = v1 ? expf(ed1 - md) : 0.0f;
  float Sd = wd0 + wd1;
  for (int off = 32; off > 0; off >>= 1) Sd += __shfl_xor(Sd, off, 64);
  att[wid][1][j0] = wd0 / Sd;
  if (v1) att[wid][1][j1] = wd1 / Sd;
  // all waves done with bufA (nd): overwrite with h_d
  __syncthreads();
  {
    const float4* hdv = (const float4*)(h_d + base * DD);
    for (int idx = tid; idx < NN * DD / 4; idx += 256) {
      float4 v = hdv[idx];
      int row = idx >> 4, c4 = (idx & 15) * 4;
      float* dA = &bufA[row * 65 + c4];
      dA[0] = v.x; dA[1] = v.y; dA[2] = v.z; dA[3] = v.w;
    }
  }
  __syncthreads();
  // PV: lane = channel; att wave-uniform LDS broadcast, h rows from LDS.
  // Identical accumulation order (j ascending) and fp values to r2.
  float hs = 0.0f, hd2 = 0.0f;
#pragma unroll 4
  for (int j = 0; j < NN; ++j) {
    hs = fmaf(att[wid][0][j], bufB[j * 65 + lane], hs);
    hd2 = fmaf(att[wid][1][j], bufA[j * 65 + lane], hd2);
  }
  float eS = (hs > 0.0f) ? hs : expm1f(hs);
  float eD = (hd2 > 0.0f) ? hd2 : expm1f(hd2);
  float ov = (eS + 0.01f * eD) * ne[r * DD + lane];
  o[i * DD + lane] = ov;
  // BN partials: block reduce (reuse att), 128 device-scope atomics
  __syncthreads();
  att[wid][0][lane] = ov;
  att[wid][1][lane] = ov * ov;
  __syncthreads();
  if (wid == 0) {
    float s = att[0][0][lane] + att[1][0][lane] + att[2][0][lane] + att[3][0][lane];
    unsafeAtomicAdd(&gstat[lane], s);
  } else if (wid == 1) {
    float s = att[0][1][lane] + att[1][1][lane] + att[2][1][lane] + att[3][1][lane];
    unsafeAtomicAdd(&gstat[64 + lane], s);
  }
}

// ---------------- K3: BN finalize + apply + ReLU + out projection ----------------
__global__ __launch_bounds__(256) void k_final(
    const float* __restrict__ o, const float* __restrict__ gstat,
    const float* __restrict__ gamma, const float* __restrict__ beta,
    const float* __restrict__ outW, const float* __restrict__ outb,
    float* __restrict__ out) {
  int tid = threadIdx.x, wid = tid >> 6, lane = tid & 63;
  int i = blockIdx.x * 4 + wid;
  float m = gstat[lane] * (1.0f / NT);
  float ex2 = gstat[64 + lane] * (1.0f / NT);
  float var = ex2 - m * m;
  float scale = gamma[lane] / sqrtf(var + 1e-5f);
  float xv = o[i * DD + lane];
  float v = (xv - m) * scale + beta[lane];
  v = fmaxf(v, 0.0f);
  float p = v * outW[lane];
  for (int off = 32; off > 0; off >>= 1) p += __shfl_xor(p, off, 64);
  if (lane == 0) out[i] = p + outb[0];
}

extern "C" void kernel_launch(void* const* d_in, const int* in_sizes, int n_in,
                              void* d_out, int out_size, void* d_ws,
                              size_t ws_size, hipStream_t stream) {
  const float* data = (const float*)d_in[0];
  const float* node_emb = (const float*)d_in[1];
  const float* lin_W = (const float*)d_in[2];
  const float* lin_b = (const float*)d_in[3];
  const float* gat_s_W = (const float*)d_in[4];
  const float* gat_s_b = (const float*)d_in[5];
  const float* gat_s_a = (const float*)d_in[6];
  const float* gat_d_W = (const float*)d_in[7];
  const float* gat_d_b = (const float*)d_in[8];
  const float* gat_d_a = (const float*)d_in[9];
  const float* bn_gamma = (const float*)d_in[10];
  const float* bn_beta = (const float*)d_in[11];
  const float* out_W = (const float*)d_in[12];
  const float* out_b = (const float*)d_in[13];
  float* out = (float*)d_out;

  float* ws = (float*)d_ws;
  float* h_s = ws;                 // NT*DD
  float* h_d = ws + 204800;        // NT*DD
  float* nd = ws + 409600;         // NT*DD
  float* q_s = ws + 614400;        // NT
  float* kk_s = ws + 617600;       // NT
  float* q_d = ws + 620800;        // NT
  float* kk_d = ws + 624000;       // NT
  float* adjS = ws + 627200;       // NN*NN
  float* o = ws + 637200;          // NT*DD
  float* gstat = ws + 842000;      // 128 (sum[64], sumsq[64])

  // JAX key(42): partitionable split -> k1=cipher(key,(0,0)), k2=cipher(key,(0,1))
  uint32_t k1a, k1b, k2a, k2b;
  tf2x32(0u, 42u, 0u, 0u, k1a, k1b);
  tf2x32(0u, 42u, 0u, 1u, k2a, k2b);

  k_prep_adj<<<840, 256, 0, stream>>>(data, node_emb, lin_W, lin_b, gat_s_W,
                                      gat_s_b, gat_s_a, gat_d_W, gat_d_b,
                                      gat_d_a, h_s, h_d, nd, q_s, kk_s, q_d,
                                      kk_d, adjS, gstat, k1a, k1b);
  k_attn<<<800, 256, 0, stream>>>(h_s, h_d, nd, q_s, kk_s, q_d, kk_d, adjS,
                                  node_emb, o, gstat, k2a, k2b);
  k_final<<<800, 256, 0, stream>>>(o, gstat, bn_gamma, bn_beta, out_W, out_b,
                                   out);
}

// Round 11
// 125.555 us; speedup vs baseline: 1.5099x; 1.0542x over previous
//
#include <hip/hip_runtime.h>
#include <cstdint>

// Problem constants (fixed by reference)
#define NT 3200   // B*N
#define NN 100    // N
#define FD 10     // F_IN
#define DD 64     // D
#define NCOPY 32  // BN atomic sink replicas (contention spreading)

// ---------------- threefry2x32 (JAX PRNG), host+device ----------------
__host__ __device__ inline void tf2x32(uint32_t ks0, uint32_t ks1, uint32_t x0,
                                       uint32_t x1, uint32_t& o0, uint32_t& o1) {
  uint32_t ks2 = ks0 ^ ks1 ^ 0x1BD11BDAu;
  x0 += ks0; x1 += ks1;
#define TF_RND(r) { x0 += x1; x1 = (x1 << (r)) | (x1 >> (32 - (r))); x1 ^= x0; }
  TF_RND(13) TF_RND(15) TF_RND(26) TF_RND(6)
  x0 += ks1; x1 += ks2 + 1u;
  TF_RND(17) TF_RND(29) TF_RND(16) TF_RND(24)
  x0 += ks2; x1 += ks0 + 2u;
  TF_RND(13) TF_RND(15) TF_RND(26) TF_RND(6)
  x0 += ks0; x1 += ks1 + 3u;
  TF_RND(17) TF_RND(29) TF_RND(16) TF_RND(24)
  x0 += ks1; x1 += ks2 + 4u;
  TF_RND(13) TF_RND(15) TF_RND(26) TF_RND(6)
  x0 += ks2; x1 += ks0 + 5u;
#undef TF_RND
  o0 = x0; o1 = x1;
}

// JAX partitionable random_bits(32) for counter (0, cnt); uniform(1e-20,1); gumbel.
__device__ inline float gumbel_noise(uint32_t ka, uint32_t kb, uint32_t cnt) {
  uint32_t o0, o1;
  tf2x32(ka, kb, 0u, cnt, o0, o1);
  uint32_t bits = o0 ^ o1;
  float u = __uint_as_float((bits >> 9) | 0x3F800000u) - 1.0f;
  u = fmaxf(u, 1e-20f);
  return -logf(-logf(u));
}

// ---------------- K1: per-row prep (blocks 0..799) + static adj (800..839) ----
__global__ __launch_bounds__(256) void k_prep_adj(
    const float* __restrict__ x, const float* __restrict__ ne,
    const float* __restrict__ lW, const float* __restrict__ lb,
    const float* __restrict__ Ws, const float* __restrict__ bs,
    const float* __restrict__ as_, const float* __restrict__ Wd,
    const float* __restrict__ bd, const float* __restrict__ ad,
    float* __restrict__ h_s, float* __restrict__ h_d, float* __restrict__ nd,
    float* __restrict__ q_s, float* __restrict__ kk_s, float* __restrict__ q_d,
    float* __restrict__ kk_d, float* __restrict__ adjS,
    float* __restrict__ gstat, uint32_t k1a, uint32_t k1b) {
  __shared__ float sne[NN * 65];
  __shared__ float dnorm[NN];
  int tid = threadIdx.x, wid = tid >> 6, lane = tid & 63;
  int blk = blockIdx.x;
  if (blk < 800) {
    // wave-per-row prep: h_s, h_d, normalized dyn-emb, attention projections
    int i = blk * 4 + wid;
    const float* xr = x + i * FD;
    float hs = bs[lane], hd = bd[lane], ed = lb[lane];
#pragma unroll
    for (int f = 0; f < FD; ++f) {
      float xv = xr[f];
      hs = fmaf(xv, Ws[f * DD + lane], hs);
      hd = fmaf(xv, Wd[f * DD + lane], hd);
      ed = fmaf(xv, lW[f * DD + lane], ed);
    }
    h_s[i * DD + lane] = hs;
    h_d[i * DD + lane] = hd;
    float ss = ed * ed;
    for (int off = 32; off > 0; off >>= 1) ss += __shfl_xor(ss, off, 64);
    nd[i * DD + lane] = ed / (sqrtf(ss) + 1e-8f);
    int r = i % NN;
    float em = ne[r * DD + lane];
    float ks = hs + em, kd = hd + em;
    float qs = ks * as_[lane], kks = ks * as_[DD + lane];
    float qd = kd * ad[lane], kkd = kd * ad[DD + lane];
    for (int off = 32; off > 0; off >>= 1) {
      qs += __shfl_xor(qs, off, 64);
      kks += __shfl_xor(kks, off, 64);
      qd += __shfl_xor(qd, off, 64);
      kkd += __shfl_xor(kkd, off, 64);
    }
    if (lane == 0) { q_s[i] = qs; kk_s[i] = kks; q_d[i] = qd; kk_d[i] = kkd; }
  } else {
    if (blk == 800) {  // zero all BN accumulator replicas
      for (int t = tid; t < NCOPY * 128; t += 256) gstat[t] = 0.0f;
    }
    // static adjacency: stage+normalize node_emb in LDS, 100x100 decisions
    {
      const float4* nev = (const float4*)ne;
      for (int idx = tid; idx < NN * DD / 4; idx += 256) {
        float4 v = nev[idx];
        int row = idx >> 4, c4 = (idx & 15) * 4;
        float* dst = &sne[row * 65 + c4];
        dst[0] = v.x; dst[1] = v.y; dst[2] = v.z; dst[3] = v.w;
      }
    }
    __syncthreads();
    for (int row = wid; row < NN; row += 4) {
      float v = sne[row * 65 + lane];
      float ss = v * v;
      for (int off = 32; off > 0; off >>= 1) ss += __shfl_xor(ss, off, 64);
      if (lane == 0) dnorm[row] = sqrtf(ss) + 1e-8f;
    }
    __syncthreads();
    for (int idx = tid; idx < NN * DD; idx += 256) {
      int row = idx >> 6;
      sne[row * 65 + (idx & 63)] /= dnorm[row];
    }
    __syncthreads();
    int p = (blk - 800) * 256 + tid;
    if (p < NN * NN) {
      int r = p / NN, c = p - r * NN;
      float sim = 0.0f;
#pragma unroll
      for (int k = 0; k < DD; ++k)
        sim = fmaf(sne[r * 65 + k], sne[c * 65 + k], sim);
      float g0 = gumbel_noise(k1a, k1b, (uint32_t)(2 * p));
      float g1 = gumbel_noise(k1a, k1b, (uint32_t)(2 * p + 1));
      bool edge = (sim + g0 >= 1.0f - sim + g1) || (r == c);
      adjS[p] = edge ? 1.0f : 0.0f;
    }
  }
}

// ---------------- K2: wave-per-row attention (LDS-resident PV) ----------------
__global__ __launch_bounds__(256) void k_attn(
    const float* __restrict__ h_s, const float* __restrict__ h_d,
    const float* __restrict__ nd, const float* __restrict__ q_s,
    const float* __restrict__ kk_s, const float* __restrict__ q_d,
    const float* __restrict__ kk_d, const float* __restrict__ adjS,
    const float* __restrict__ ne, float* __restrict__ o,
    float* __restrict__ gstat, uint32_t k2a, uint32_t k2b) {
  __shared__ float bufA[NN * 65];  // nd during sims, then h_d for PV
  __shared__ float bufB[NN * 65];  // h_s (staged early; loads overlap sims/RNG)
  __shared__ float att[4][2][NN];  // per-wave attention rows; reused for stats
  int tid = threadIdx.x, wid = tid >> 6, lane = tid & 63;
  int blk = blockIdx.x;
  int b = blk / 25, rb = (blk % 25) * 4;
  int base = b * NN;
  // stage nd -> bufA and h_s -> bufB (independent; float4 global loads)
  {
    const float4* ndv = (const float4*)(nd + base * DD);
    const float4* hsv = (const float4*)(h_s + base * DD);
    for (int idx = tid; idx < NN * DD / 4; idx += 256) {
      float4 v = ndv[idx];
      float4 w = hsv[idx];
      int row = idx >> 4, c4 = (idx & 15) * 4;
      float* dA = &bufA[row * 65 + c4];
      float* dB = &bufB[row * 65 + c4];
      dA[0] = v.x; dA[1] = v.y; dA[2] = v.z; dA[3] = v.w;
      dB[0] = w.x; dB[1] = w.y; dB[2] = w.z; dB[3] = w.w;
    }
  }
  __syncthreads();

  int r = rb + wid;
  int i = base + r;  // == blk*4 + wid
  float sqs = q_s[i], sqd = q_d[i];
  int j0 = lane, j1 = lane + 64;
  bool v1 = (j1 < NN);
  int jj1 = v1 ? j1 : 0;
  // cosine sims vs row r (LDS: broadcast + stride-65)
  float sim0 = 0.0f, sim1 = 0.0f;
  const float* ndr = &bufA[r * 65];
  const float* nj0 = &bufA[j0 * 65];
  const float* nj1 = &bufA[jj1 * 65];
#pragma unroll
  for (int k = 0; k < DD; ++k) {
    float a = ndr[k];
    sim0 = fmaf(a, nj0[k], sim0);
    sim1 = fmaf(a, nj1[k], sim1);
  }
  // static edges (precomputed adjacency)
  float es0 = -9e15f, es1 = -9e15f, ed0 = -9e15f, ed1 = -9e15f;
  if (adjS[r * NN + j0] > 0.0f) {
    float v = sqs + kk_s[base + j0];
    es0 = (v >= 0.0f) ? v : 0.2f * v;
  }
  if (v1 && adjS[r * NN + j1] > 0.0f) {
    float v = sqs + kk_s[base + j1];
    es1 = (v >= 0.0f) ? v : 0.2f * v;
  }
  // dynamic edges (gumbel on the fly)
  {
    uint32_t c0 = ((uint32_t)i * 3200u + (uint32_t)(base + j0)) * 2u;
    float g0 = gumbel_noise(k2a, k2b, c0);
    float g1 = gumbel_noise(k2a, k2b, c0 + 1u);
    if (sim0 + g0 >= 1.0f - sim0 + g1) {
      float v = sqd + kk_d[base + j0];
      ed0 = (v >= 0.0f) ? v : 0.2f * v;
    }
  }
  if (v1) {
    uint32_t c1 = ((uint32_t)i * 3200u + (uint32_t)(base + j1)) * 2u;
    float g0 = gumbel_noise(k2a, k2b, c1);
    float g1 = gumbel_noise(k2a, k2b, c1 + 1u);
    if (sim1 + g0 >= 1.0f - sim1 + g1) {
      float v = sqd + kk_d[base + j1];
      ed1 = (v >= 0.0f) ? v : 0.2f * v;
    }
  }
  // wave softmax, static (registers only)
  float ms = fmaxf(es0, es1);
  for (int off = 32; off > 0; off >>= 1) ms = fmaxf(ms, __shfl_xor(ms, off, 64));
  float ws0 = expf(es0 - ms);
  float ws1 = v1 ? expf(es1 - ms) : 0.0f;
  float Ss = ws0 + ws1;
  for (int off = 32; off > 0; off >>= 1) Ss += __shfl_xor(Ss, off, 64);
  att[wid][0][j0] = ws0 / Ss;
  if (v1) att[wid][0][j1] = ws1 / Ss;
  // wave softmax, dynamic
  float md = fmaxf(ed0, ed1);
  for (int off = 32; off > 0; off >>= 1) md = fmaxf(md, __shfl_xor(md, off, 64));
  float wd0 = expf(ed0 - md);
  float wd1 = v1 ? expf(ed1 - md) : 0.0f;
  float Sd = wd0 + wd1;
  for (int off = 32; off > 0; off >>= 1) Sd += __shfl_xor(Sd, off, 64);
  att[wid][1][j0] = wd0 / Sd;
  if (v1) att[wid][1][j1] = wd1 / Sd;
  // all waves done with bufA (nd): overwrite with h_d
  __syncthreads();
  {
    const float4* hdv = (const float4*)(h_d + base * DD);
    for (int idx = tid; idx < NN * DD / 4; idx += 256) {
      float4 v = hdv[idx];
      int row = idx >> 4, c4 = (idx & 15) * 4;
      float* dA = &bufA[row * 65 + c4];
      dA[0] = v.x; dA[1] = v.y; dA[2] = v.z; dA[3] = v.w;
    }
  }
  __syncthreads();
  // PV: lane = channel; att wave-uniform LDS broadcast, h rows from LDS.
  // Identical accumulation order (j ascending) and fp values to r2.
  float hs = 0.0f, hd2 = 0.0f;
#pragma unroll 4
  for (int j = 0; j < NN; ++j) {
    hs = fmaf(att[wid][0][j], bufB[j * 65 + lane], hs);
    hd2 = fmaf(att[wid][1][j], bufA[j * 65 + lane], hd2);
  }
  float eS = (hs > 0.0f) ? hs : expm1f(hs);
  float eD = (hd2 > 0.0f) ? hd2 : expm1f(hd2);
  float ov = (eS + 0.01f * eD) * ne[r * DD + lane];
  o[i * DD + lane] = ov;
  // BN partials: block reduce (reuse att), atomics into blk&31 replica
  __syncthreads();
  att[wid][0][lane] = ov;
  att[wid][1][lane] = ov * ov;
  __syncthreads();
  float* gs = gstat + (blk & (NCOPY - 1)) * 128;
  if (wid == 0) {
    float s = att[0][0][lane] + att[1][0][lane] + att[2][0][lane] + att[3][0][lane];
    unsafeAtomicAdd(&gs[lane], s);
  } else if (wid == 1) {
    float s = att[0][1][lane] + att[1][1][lane] + att[2][1][lane] + att[3][1][lane];
    unsafeAtomicAdd(&gs[64 + lane], s);
  }
}

// ---------------- K3: BN finalize + apply + ReLU + out projection ----------------
__global__ __launch_bounds__(256) void k_final(
    const float* __restrict__ o, const float* __restrict__ gstat,
    const float* __restrict__ gamma, const float* __restrict__ beta,
    const float* __restrict__ outW, const float* __restrict__ outb,
    float* __restrict__ out) {
  int tid = threadIdx.x, wid = tid >> 6, lane = tid & 63;
  int i = blockIdx.x * 4 + wid;
  float sm = 0.0f, s2 = 0.0f;
#pragma unroll
  for (int c = 0; c < NCOPY; ++c) {
    sm += gstat[c * 128 + lane];
    s2 += gstat[c * 128 + 64 + lane];
  }
  float m = sm * (1.0f / NT);
  float ex2 = s2 * (1.0f / NT);
  float var = ex2 - m * m;
  float scale = gamma[lane] / sqrtf(var + 1e-5f);
  float xv = o[i * DD + lane];
  float v = (xv - m) * scale + beta[lane];
  v = fmaxf(v, 0.0f);
  float p = v * outW[lane];
  for (int off = 32; off > 0; off >>= 1) p += __shfl_xor(p, off, 64);
  if (lane == 0) out[i] = p + outb[0];
}

extern "C" void kernel_launch(void* const* d_in, const int* in_sizes, int n_in,
                              void* d_out, int out_size, void* d_ws,
                              size_t ws_size, hipStream_t stream) {
  const float* data = (const float*)d_in[0];
  const float* node_emb = (const float*)d_in[1];
  const float* lin_W = (const float*)d_in[2];
  const float* lin_b = (const float*)d_in[3];
  const float* gat_s_W = (const float*)d_in[4];
  const float* gat_s_b = (const float*)d_in[5];
  const float* gat_s_a = (const float*)d_in[6];
  const float* gat_d_W = (const float*)d_in[7];
  const float* gat_d_b = (const float*)d_in[8];
  const float* gat_d_a = (const float*)d_in[9];
  const float* bn_gamma = (const float*)d_in[10];
  const float* bn_beta = (const float*)d_in[11];
  const float* out_W = (const float*)d_in[12];
  const float* out_b = (const float*)d_in[13];
  float* out = (float*)d_out;

  float* ws = (float*)d_ws;
  float* h_s = ws;                 // NT*DD
  float* h_d = ws + 204800;        // NT*DD
  float* nd = ws + 409600;         // NT*DD
  float* q_s = ws + 614400;        // NT
  float* kk_s = ws + 617600;       // NT
  float* q_d = ws + 620800;        // NT
  float* kk_d = ws + 624000;       // NT
  float* adjS = ws + 627200;       // NN*NN
  float* o = ws + 637200;          // NT*DD
  float* gstat = ws + 842000;      // NCOPY*128 (sum[64], sumsq[64] per copy)

  // JAX key(42): partitionable split -> k1=cipher(key,(0,0)), k2=cipher(key,(0,1))
  uint32_t k1a, k1b, k2a, k2b;
  tf2x32(0u, 42u, 0u, 0u, k1a, k1b);
  tf2x32(0u, 42u, 0u, 1u, k2a, k2b);

  k_prep_adj<<<840, 256, 0, stream>>>(data, node_emb, lin_W, lin_b, gat_s_W,
                                      gat_s_b, gat_s_a, gat_d_W, gat_d_b,
                                      gat_d_a, h_s, h_d, nd, q_s, kk_s, q_d,
                                      kk_d, adjS, gstat, k1a, k1b);
  k_attn<<<800, 256, 0, stream>>>(h_s, h_d, nd, q_s, kk_s, q_d, kk_d, adjS,
                                  node_emb, o, gstat, k2a, k2b);
  k_final<<<800, 256, 0, stream>>>(o, gstat, bn_gamma, bn_beta, out_W, out_b,
                                   out);
}